// Round 5
// baseline (392.226 us; speedup 1.0000x reference)
//
#include <hip/hip_runtime.h>
#include <stdint.h>

#define Bb   2
#define Tt   2048
#define Cc_  2048
#define Hh   16
#define Dd   128
#define Mm_  4096            // B*T
#define N1   6144            // 3*C
#define EPSf 1.1920929e-07f
#define SCALE (1.0f/128.0f)  // reference uses 1/D, not 1/sqrt(D)

typedef __bf16 bf16;
typedef __attribute__((ext_vector_type(8))) __bf16 bf16x8;
typedef __attribute__((ext_vector_type(4))) float  f32x4;

// ---- async global->LDS, width 16. LDS dest = wave-uniform base + lane*16.
__device__ __forceinline__ void gl_lds16(const bf16* g, bf16* l) {
  __builtin_amdgcn_global_load_lds(
      (const __attribute__((address_space(1))) unsigned int*)g,
      (__attribute__((address_space(3))) unsigned int*)l, 16, 0, 0);
}

// ------------------------------------------------------------------ cvt x->bf16
__global__ __launch_bounds__(256) void cvt_bf16(const float* __restrict__ in,
                                                bf16* __restrict__ out, int n) {
  int i = (blockIdx.x * 256 + threadIdx.x) * 4;
  if (i >= n) return;
  float4 v = *(const float4*)(in + i);
  union { bf16 h[4]; uint2 u; } o;
  o.h[0] = (bf16)v.x; o.h[1] = (bf16)v.y; o.h[2] = (bf16)v.z; o.h[3] = (bf16)v.w;
  *(uint2*)(out + i) = o.u;
}

// -------------------------------------------- transpose+convert: [R][Cc]f32 -> [Cc][R]bf16
__global__ __launch_bounds__(256) void transpose_cvt(const float* __restrict__ in,
                                                     bf16* __restrict__ out,
                                                     int R, int Cc) {
  __shared__ float tile[64][65];
  int c0 = blockIdx.x * 64, r0 = blockIdx.y * 64;
  int tid = threadIdx.x;
#pragma unroll
  for (int j = 0; j < 16; ++j) {
    int idx = tid + j * 256;
    int r = idx >> 6, c = idx & 63;
    tile[r][c] = in[(size_t)(r0 + r) * Cc + c0 + c];
  }
  __syncthreads();
#pragma unroll
  for (int j = 0; j < 16; ++j) {
    int idx = tid + j * 256;
    int rr = idx & 63, cc = idx >> 6;
    out[(size_t)(c0 + cc) * R + r0 + rr] = (bf16)tile[rr][cc];
  }
}

// ------------------------------------------------------------------ fused QKV GEMM
// qkv = x @ w_qkv with the 128^2 m97-structure core, then PER-TILE epilogue:
// each output tile (128 rows t) x (128 cols) is exactly one head-slice:
//   s = blockIdx.x: s<16 -> Q head s; s<32 -> K head s-16; else V head s-32.
// Q/K: RMSNorm over the 128 cols (all inside the tile) + RoPE pairs (d,d+64)
//      (also inside the tile) -> write Qg/Kg [bh][t][d].
// V:   transposed write -> VgT [bh][d][t].
// Epilogue stages acc through a 128x129 bf16 LDS tile that UNIONS with As/Bs
// (dead after the K-loop). Precision = old pipeline (acc f32 -> bf16 -> f32 norm).
__global__ __launch_bounds__(256) void gemm_qkv_fused(
    const bf16* __restrict__ A, const bf16* __restrict__ Bt,
    const float* __restrict__ qw, const float* __restrict__ kw,
    bf16* __restrict__ Qg, bf16* __restrict__ Kg, bf16* __restrict__ VgT) {
  __shared__ __align__(16) bf16 smem[128 * 129];   // 33 KB: loop needs 16384, epi 16512
  bf16* As = smem;
  bf16* Bs = smem + 128 * 64;
  const int Kk = Cc_;
  const int tid = threadIdx.x;
  const int wave = tid >> 6, lane = tid & 63;
  const int quad = lane >> 4, li = lane & 15;
  const int wm = wave >> 1, wn = wave & 1;
  const int m0 = blockIdx.y * 128, n0 = blockIdx.x * 128;

  f32x4 acc[4][4] = {};

  for (int kt = 0; kt < Kk; kt += 64) {
    __syncthreads();
#pragma unroll
    for (int j = 0; j < 4; ++j) {
      int c = j * 256 + tid;
      int r = c >> 3, cc = c & 7;
      int gc = ((cc ^ (r & 7)) << 3);
      gl_lds16(A + (size_t)(m0 + r) * Kk + kt + gc, &As[c * 8]);
      gl_lds16(Bt + (size_t)(n0 + r) * Kk + kt + gc, &Bs[c * 8]);
    }
    __syncthreads();
#pragma unroll
    for (int kc = 0; kc < 2; ++kc) {
      bf16x8 af[4], bfr[4];
#pragma unroll
      for (int t = 0; t < 4; ++t) {
        int rowa = wm * 64 + t * 16 + li;
        af[t] = *(const bf16x8*)&As[rowa * 64 + (((kc * 4 + quad) ^ (rowa & 7)) << 3)];
        int rowb = wn * 64 + t * 16 + li;
        bfr[t] = *(const bf16x8*)&Bs[rowb * 64 + (((kc * 4 + quad) ^ (rowb & 7)) << 3)];
      }
#pragma unroll
      for (int mi = 0; mi < 4; ++mi)
#pragma unroll
        for (int ni = 0; ni < 4; ++ni)
          acc[mi][ni] = __builtin_amdgcn_mfma_f32_16x16x32_bf16(af[mi], bfr[ni],
                                                                acc[mi][ni], 0, 0, 0);
    }
  }

  // ---------------- epilogue: acc -> LDS tile (bf16, pad 129 vs bank conflicts)
  __syncthreads();                       // all As/Bs reads done before overwrite
  bf16 (*tile)[129] = (bf16(*)[129])smem;
#pragma unroll
  for (int mi = 0; mi < 4; ++mi) {
    int row = wm * 64 + mi * 16 + quad * 4;
#pragma unroll
    for (int ni = 0; ni < 4; ++ni) {
      int col = wn * 64 + ni * 16 + li;
#pragma unroll
      for (int r = 0; r < 4; ++r)
        tile[row + r][col] = (bf16)acc[mi][ni][r];
    }
  }
  __syncthreads();

  const int s = blockIdx.x;              // 0..47: which head-slice
  const int b = m0 >> 11;                // all 128 rows share b (T=2048, m0%128==0)
  const int tloc = m0 & 2047;            // local t of tile row 0

  if (s < 32) {
    // ---- Q or K: per-row RMSNorm + RoPE. Each wave owns 32 rows.
    const float* w = (s < 16) ? qw : kw;
    bf16* Og = (s < 16) ? Qg : Kg;
    const int h = s & 15;
    const float w1 = w[lane], w2 = w[lane + 64];
    const float invf = exp2f((float)lane * (-19.9315685693241740f / 64.0f));
    const size_t hb = (size_t)(b * Hh + h) * Tt;
    for (int rr = 0; rr < 32; ++rr) {
      int row = wave * 32 + rr;
      float x1 = (float)tile[row][lane], x2 = (float)tile[row][lane + 64];
      float ss = x1 * x1 + x2 * x2;
#pragma unroll
      for (int o = 1; o < 64; o <<= 1) ss += __shfl_xor(ss, o);
      float rn = rsqrtf(ss * (1.0f / 128.0f) + EPSf);
      x1 *= rn * w1; x2 *= rn * w2;
      int t = tloc + row;
      float sn, cs;
      sincosf((float)t * invf, &sn, &cs);
      size_t o1 = (hb + t) * Dd + lane;
      Og[o1]      = (bf16)(x1 * cs - x2 * sn);
      Og[o1 + 64] = (bf16)(x2 * cs + x1 * sn);
    }
  } else {
    // ---- V: transposed write [bh][d][t], coalesced along t (bf16x8 per thread)
    const int h = s - 32;
    const size_t hb = (size_t)(b * Hh + h) * Dd;
#pragma unroll
    for (int it = 0; it < 8; ++it) {
      int d = it * 16 + (tid >> 4);
      int t0 = (tid & 15) * 8;
      bf16x8 v;
#pragma unroll
      for (int j = 0; j < 8; ++j) v[j] = tile[t0 + j][d];
      *(bf16x8*)(VgT + (hb + d) * Tt + tloc + t0) = v;
    }
  }
}

// ------------------------------------------------------------------ GEMM 256x128, 8-wave
// (round-4 schedule, kept for the proj GEMM: 16x16 = 256 wg = 1 clean round)
template <typename OutT>
__global__ __launch_bounds__(512, 2) void gemm256(const bf16* __restrict__ A,
                                                  const bf16* __restrict__ Bt,
                                                  OutT* __restrict__ Cm,
                                                  int Nn, int Kk) {
  __shared__ __align__(16) bf16 As[2][256 * 64];
  __shared__ __align__(16) bf16 Bs[2][128 * 64];
  const int tid = threadIdx.x;
  const int wave = tid >> 6, lane = tid & 63;
  const int quad = lane >> 4, li = lane & 15;
  const int wm = wave >> 2, wn = wave & 3;  // 2(M) x 4(N)

  const int nwg = gridDim.x * gridDim.y;
  const int wg  = blockIdx.y * gridDim.x + blockIdx.x;
  const int swz = (wg & 7) * (nwg >> 3) + (wg >> 3);
  const int m0 = (swz / gridDim.x) * 256;
  const int n0 = (swz % gridDim.x) * 128;

  const int NT = Kk >> 6;
  const int lrow = lane >> 3;
  const int lchk = (lane & 7) ^ lrow;

  auto stageA = [&](int tt, int h, int cb) {
    int kt = (tt < NT ? tt : NT - 1) << 6;
#pragma unroll
    for (int j = 0; j < 2; ++j) {
      int seg = j * 8 + wave;
      int r0 = ((seg >> 3) << 7) + (h << 6) + ((seg & 7) << 3);
      gl_lds16(A + (size_t)(m0 + r0 + lrow) * Kk + kt + (lchk << 3),
               &As[cb][r0 * 64]);
    }
  };
  auto stageB = [&](int tt, int cb) {
    int kt = (tt < NT ? tt : NT - 1) << 6;
#pragma unroll
    for (int j = 0; j < 2; ++j) {
      int seg = j * 8 + wave;
      int r0 = seg << 3;
      gl_lds16(Bt + (size_t)(n0 + r0 + lrow) * Kk + kt + (lchk << 3),
               &Bs[cb][r0 * 64]);
    }
  };

  f32x4 acc[8][2] = {};
  bf16x8 afr[4][2], bfr[2][2];

  auto rdA = [&](int h, int cb) {
#pragma unroll
    for (int mi = 0; mi < 4; ++mi) {
      int r = wm * 128 + h * 64 + mi * 16 + li;
#pragma unroll
      for (int kc = 0; kc < 2; ++kc)
        afr[mi][kc] = *(const bf16x8*)&As[cb][r * 64 + (((kc * 4 + quad) ^ (r & 7)) << 3)];
    }
  };
  auto rdB = [&](int cb) {
#pragma unroll
    for (int nj = 0; nj < 2; ++nj) {
      int r = wn * 32 + nj * 16 + li;
#pragma unroll
      for (int kc = 0; kc < 2; ++kc)
        bfr[nj][kc] = *(const bf16x8*)&Bs[cb][r * 64 + (((kc * 4 + quad) ^ (r & 7)) << 3)];
    }
  };
  auto mmac = [&](int mo) {
    __builtin_amdgcn_s_setprio(1);
#pragma unroll
    for (int kc = 0; kc < 2; ++kc)
#pragma unroll
      for (int mi = 0; mi < 4; ++mi)
#pragma unroll
        for (int nj = 0; nj < 2; ++nj)
          acc[mo + mi][nj] = __builtin_amdgcn_mfma_f32_16x16x32_bf16(
              afr[mi][kc], bfr[nj][kc], acc[mo + mi][nj], 0, 0, 0);
    __builtin_amdgcn_s_setprio(0);
  };

  auto tile = [&](int t, int cur, int nxt) {
    rdA(0, cur); rdB(cur);
    stageA(t + 1, 1, nxt);
    asm volatile("s_waitcnt lgkmcnt(8)" ::: "memory");
    __builtin_amdgcn_s_barrier();
    asm volatile("s_waitcnt lgkmcnt(0)" ::: "memory");
    __builtin_amdgcn_sched_barrier(0);
    mmac(0);
    asm volatile("s_waitcnt vmcnt(6)" ::: "memory");
    __builtin_amdgcn_s_barrier();
    rdA(1, cur);
    stageA(t + 2, 0, cur);
    stageB(t + 2, cur);
    __builtin_amdgcn_s_barrier();
    asm volatile("s_waitcnt lgkmcnt(0)" ::: "memory");
    __builtin_amdgcn_sched_barrier(0);
    mmac(4);
    asm volatile("s_waitcnt vmcnt(6)" ::: "memory");
    __builtin_amdgcn_s_barrier();
  };

  stageA(0, 0, 0); stageB(0, 0); stageA(0, 1, 0);
  stageA(1, 0, 1); stageB(1, 1);
  asm volatile("s_waitcnt vmcnt(6)" ::: "memory");
  __builtin_amdgcn_s_barrier();

  for (int t = 0; t < NT; t += 2) {
    tile(t, 0, 1);
    tile(t + 1, 1, 0);
  }
  asm volatile("s_waitcnt vmcnt(0)" ::: "memory");

#pragma unroll
  for (int mi = 0; mi < 8; ++mi) {
    int row = m0 + wm * 128 + mi * 16 + quad * 4;
#pragma unroll
    for (int nj = 0; nj < 2; ++nj) {
      int col = n0 + wn * 32 + nj * 16 + li;
#pragma unroll
      for (int r = 0; r < 4; ++r)
        Cm[(size_t)(row + r) * Nn + col] = (OutT)acc[mi][nj][r];
    }
  }
}

// ------------------------------------------------------------------ attention
// Single q-tile per block, grid 32bh x 32qt (qt descending), 1024 blocks.
// Exact-bound softmax: q,k RMS-normed (w=1) + RoPE norm-preserving + scale
// 1/128 => |s| <= ~1.01 (Cauchy-Schwarz). No max tracking, no o-rescale;
// L accumulated per-lane, reduced ONCE at the end.
// T14 async-staged pipeline (see round-3 notes).
__global__ __launch_bounds__(256, 3) void attn(const bf16* __restrict__ Qg,
                                               const bf16* __restrict__ Kg,
                                               const bf16* __restrict__ VgT,
                                               bf16* __restrict__ Yg) {
  __shared__ __align__(16) bf16 Kl[64 * 128];
  __shared__ __align__(16) bf16 Vl[128 * 64];
  __shared__ __align__(16) bf16 Pl[4 * 16 * 72];
  const int bh = blockIdx.x;
  const int qt = (int)gridDim.y - 1 - (int)blockIdx.y;  // long blocks first
  const int b = bh >> 4, h = bh & 15;
  const int tid = threadIdx.x, wave = tid >> 6, lane = tid & 63;
  const int quad = lane >> 4, li = lane & 15;
  const int q0 = qt * 64;

  const bf16* Qbase = Qg + ((size_t)bh * Tt + q0 + wave * 16 + li) * Dd;
  bf16x8 qf[4];
#pragma unroll
  for (int kc = 0; kc < 4; ++kc) qf[kc] = *(const bf16x8*)(Qbase + kc * 32 + quad * 8);

  f32x4 o[8] = {};
  float L[4] = {};
  bf16* Pw = &Pl[wave * 16 * 72];

  bf16x8 kreg[4];
  auto loadK = [&](int k0) {
#pragma unroll
    for (int j = 0; j < 4; ++j) {
      int c = j * 256 + tid;
      int r = c >> 4, cc = c & 15;
      kreg[j] = *(const bf16x8*)(Kg + ((size_t)bh * Tt + k0 + r) * Dd + ((cc ^ (r & 7)) << 3));
    }
  };
  auto stageV = [&](int k0) {
#pragma unroll
    for (int j = 0; j < 4; ++j) {
      int c = j * 256 + tid;
      int r = c >> 3, cc = c & 7;
      gl_lds16(VgT + ((size_t)bh * Dd + r) * Tt + k0 + ((cc ^ (r & 7)) << 3), &Vl[c * 8]);
    }
  };

  loadK(0);
  stageV(0);

  for (int kt = 0; kt <= qt; ++kt) {
    asm volatile("s_waitcnt vmcnt(4)" ::: "memory");
#pragma unroll
    for (int j = 0; j < 4; ++j) {
      int c = j * 256 + tid;
      *(bf16x8*)&Kl[c * 8] = kreg[j];
    }
    if (kt < qt) loadK(kt * 64 + 64);
    asm volatile("s_waitcnt lgkmcnt(0)" ::: "memory");
    __builtin_amdgcn_s_barrier();
    __builtin_amdgcn_sched_barrier(0);

    f32x4 s4[4] = {};
#pragma unroll
    for (int nt = 0; nt < 4; ++nt) {
      int key = nt * 16 + li;
#pragma unroll
      for (int kc = 0; kc < 4; ++kc) {
        bf16x8 kf = *(const bf16x8*)&Kl[key * 128 + (((kc * 4 + quad) ^ (key & 7)) << 3)];
        s4[nt] = __builtin_amdgcn_mfma_f32_16x16x32_bf16(qf[kc], kf, s4[nt], 0, 0, 0);
      }
    }
    const bool diag = (kt == qt);
#pragma unroll
    for (int nt = 0; nt < 4; ++nt)
#pragma unroll
      for (int r = 0; r < 4; ++r) {
        float e = __expf(s4[nt][r] * SCALE);
        if (diag && (nt * 16 + li > wave * 16 + quad * 4 + r)) e = 0.f;
        L[r] += e;
        Pw[(quad * 4 + r) * 72 + nt * 16 + li] = (bf16)e;
      }
    if (kt < qt) { asm volatile("s_waitcnt vmcnt(4)" ::: "memory"); }
    else         { asm volatile("s_waitcnt vmcnt(0)" ::: "memory"); }
    __builtin_amdgcn_s_barrier();
    __builtin_amdgcn_sched_barrier(0);

#pragma unroll
    for (int kc = 0; kc < 2; ++kc) {
      bf16x8 pf = *(const bf16x8*)&Pw[li * 72 + kc * 32 + quad * 8];
#pragma unroll
      for (int u = 0; u < 8; ++u) {
        bf16x8 vf = *(const bf16x8*)&Vl[(u * 16 + li) * 64 + (((kc * 4 + quad) ^ (li & 7)) << 3)];
        o[u] = __builtin_amdgcn_mfma_f32_16x16x32_bf16(pf, vf, o[u], 0, 0, 0);
      }
    }
    asm volatile("" ::: "memory");
    __builtin_amdgcn_s_barrier();
    __builtin_amdgcn_sched_barrier(0);
    if (kt < qt) stageV(kt * 64 + 64);
  }

  float inv[4];
#pragma unroll
  for (int r = 0; r < 4; ++r) {
    float s0 = L[r];
#pragma unroll
    for (int off = 1; off < 16; off <<= 1) s0 += __shfl_xor(s0, off);
    inv[r] = 1.0f / s0;
  }
  int trow = q0 + wave * 16 + quad * 4;
#pragma unroll
  for (int u = 0; u < 8; ++u) {
    int col = h * Dd + u * 16 + li;
#pragma unroll
    for (int r = 0; r < 4; ++r)
      Yg[(size_t)(b * Tt + trow + r) * Cc_ + col] = (bf16)(o[u][r] * inv[r]);
  }
}

// ------------------------------------------------------------------ launch
extern "C" void kernel_launch(void* const* d_in, const int* in_sizes, int n_in,
                              void* d_out, int out_size, void* d_ws, size_t ws_size,
                              hipStream_t stream) {
  const float* x      = (const float*)d_in[0];
  const float* w_qkv  = (const float*)d_in[1];
  const float* w_proj = (const float*)d_in[2];
  const float* qnw    = (const float*)d_in[3];
  const float* knw    = (const float*)d_in[4];
  float* out = (float*)d_out;

  // workspace partition (bf16 elements)
  bf16* xb     = (bf16*)d_ws;                   // dead after fused qkv GEMM
  bf16* wqkvT  = xb + (size_t)Mm_ * Cc_;
  bf16* wprojT = wqkvT + (size_t)N1 * Cc_;
  bf16* Qg     = wprojT + (size_t)Cc_ * Cc_;
  bf16* Kg     = Qg + (size_t)Bb * Hh * Tt * Dd;
  bf16* VgT    = Kg + (size_t)Bb * Hh * Tt * Dd;
  bf16* Yg     = xb;    // alias: xb dead by the time attn writes Yg

  hipLaunchKernelGGL(cvt_bf16, dim3((Mm_ * Cc_ / 4) / 256), dim3(256), 0, stream,
                     x, xb, Mm_ * Cc_);
  hipLaunchKernelGGL(transpose_cvt, dim3(N1 / 64, Cc_ / 64), dim3(256), 0, stream,
                     w_qkv, wqkvT, Cc_, N1);
  hipLaunchKernelGGL(transpose_cvt, dim3(Cc_ / 64, Cc_ / 64), dim3(256), 0, stream,
                     w_proj, wprojT, Cc_, Cc_);
  // fused: GEMM + RMSNorm + RoPE + rearrange + V-transpose (replaces 3 kernels)
  hipLaunchKernelGGL(gemm_qkv_fused, dim3(N1 / 128, Mm_ / 128), dim3(256), 0, stream,
                     xb, wqkvT, qnw, knw, Qg, Kg, VgT);
  hipLaunchKernelGGL(attn, dim3(Bb * Hh, Tt / 64), dim3(256), 0, stream,
                     Qg, Kg, VgT, Yg);
  // proj GEMM: 256x128 tile, 16x16 = 256 wg = exactly 1 round
  hipLaunchKernelGGL(gemm256<float>, dim3(Cc_ / 128, Mm_ / 256), dim3(512), 0, stream,
                     Yg, wprojT, out, Cc_, Cc_);
}

// Round 6
// 377.752 us; speedup vs baseline: 1.0383x; 1.0383x over previous
//
#include <hip/hip_runtime.h>
#include <stdint.h>

#define Bb   2
#define Tt   2048
#define Cc_  2048
#define Hh   16
#define Dd   128
#define Mm_  4096            // B*T
#define N1   6144            // 3*C
#define EPSf 1.1920929e-07f
#define SCALE (1.0f/128.0f)  // reference uses 1/D, not 1/sqrt(D)

typedef __bf16 bf16;
typedef __attribute__((ext_vector_type(8))) __bf16 bf16x8;
typedef __attribute__((ext_vector_type(4))) __bf16 bf16x4;
typedef __attribute__((ext_vector_type(4))) float  f32x4;

// ---- async global->LDS, width 16. LDS dest = wave-uniform base + lane*16.
__device__ __forceinline__ void gl_lds16(const bf16* g, bf16* l) {
  __builtin_amdgcn_global_load_lds(
      (const __attribute__((address_space(1))) unsigned int*)g,
      (__attribute__((address_space(3))) unsigned int*)l, 16, 0, 0);
}

// ------------------------------------------------------------------ cvt x->bf16
__global__ __launch_bounds__(256) void cvt_bf16(const float* __restrict__ in,
                                                bf16* __restrict__ out, int n) {
  int i = (blockIdx.x * 256 + threadIdx.x) * 4;
  if (i >= n) return;
  float4 v = *(const float4*)(in + i);
  union { bf16 h[4]; uint2 u; } o;
  o.h[0] = (bf16)v.x; o.h[1] = (bf16)v.y; o.h[2] = (bf16)v.z; o.h[3] = (bf16)v.w;
  *(uint2*)(out + i) = o.u;
}

// ------------------------------------------------------ RoPE cos/sin table
// rope[t*64 + d] = {cos(t*invf(d)), sin(t*invf(d))}, t<2048, d<64. 1 MB.
__global__ __launch_bounds__(256) void rope_tab(float2* __restrict__ rope) {
  int i = blockIdx.x * 256 + threadIdx.x;   // < 2048*64
  int t = i >> 6, d = i & 63;
  float ang = (float)t * exp2f((float)d * (-19.9315685693241740f / 64.0f));
  float sn, cs;
  sincosf(ang, &sn, &cs);
  rope[i] = make_float2(cs, sn);
}

// -------------------------------------------- transpose+convert: [R][Cc]f32 -> [Cc][R]bf16
__global__ __launch_bounds__(256) void transpose_cvt(const float* __restrict__ in,
                                                     bf16* __restrict__ out,
                                                     int R, int Cc) {
  __shared__ float tile[64][65];
  int c0 = blockIdx.x * 64, r0 = blockIdx.y * 64;
  int tid = threadIdx.x;
#pragma unroll
  for (int j = 0; j < 16; ++j) {
    int idx = tid + j * 256;
    int r = idx >> 6, c = idx & 63;
    tile[r][c] = in[(size_t)(r0 + r) * Cc + c0 + c];
  }
  __syncthreads();
#pragma unroll
  for (int j = 0; j < 16; ++j) {
    int idx = tid + j * 256;
    int rr = idx & 63, cc = idx >> 6;
    out[(size_t)(c0 + cc) * R + r0 + rr] = (bf16)tile[rr][cc];
  }
}

// ------------------------------------------------------------------ fused QKV GEMM
// qkv = x @ w_qkv (128^2 m97-structure core) + per-tile epilogue. Each output
// tile (128 t-rows x 128 cols) is one head-slice: s=blockIdx.x: s<16 Q head s,
// s<32 K head s-16, else V head s-32.
// Epilogue v2 (round-5 post-mortem): table-driven RoPE (no on-device trig),
// 16-lane-group row reduction (4 shfl, 8 iters/wave), all-vector LDS (pad 136
// keeps 16B row alignment). V blocks store acc pre-transposed in LDS.
__global__ __launch_bounds__(256) void gemm_qkv_fused(
    const bf16* __restrict__ A, const bf16* __restrict__ Bt,
    const float* __restrict__ qw, const float* __restrict__ kw,
    const float2* __restrict__ rope,
    bf16* __restrict__ Qg, bf16* __restrict__ Kg, bf16* __restrict__ VgT) {
  __shared__ __align__(16) bf16 smem[128 * 136];   // 34 KB; K-loop uses first 32 KB
  bf16* As = smem;
  bf16* Bs = smem + 128 * 64;
  const int Kk = Cc_;
  const int tid = threadIdx.x;
  const int wave = tid >> 6, lane = tid & 63;
  const int quad = lane >> 4, li = lane & 15;
  const int wm = wave >> 1, wn = wave & 1;
  const int m0 = blockIdx.y * 128, n0 = blockIdx.x * 128;

  f32x4 acc[4][4] = {};

  for (int kt = 0; kt < Kk; kt += 64) {
    __syncthreads();
#pragma unroll
    for (int j = 0; j < 4; ++j) {
      int c = j * 256 + tid;
      int r = c >> 3, cc = c & 7;
      int gc = ((cc ^ (r & 7)) << 3);
      gl_lds16(A + (size_t)(m0 + r) * Kk + kt + gc, &As[c * 8]);
      gl_lds16(Bt + (size_t)(n0 + r) * Kk + kt + gc, &Bs[c * 8]);
    }
    __syncthreads();
#pragma unroll
    for (int kc = 0; kc < 2; ++kc) {
      bf16x8 af[4], bfr[4];
#pragma unroll
      for (int t = 0; t < 4; ++t) {
        int rowa = wm * 64 + t * 16 + li;
        af[t] = *(const bf16x8*)&As[rowa * 64 + (((kc * 4 + quad) ^ (rowa & 7)) << 3)];
        int rowb = wn * 64 + t * 16 + li;
        bfr[t] = *(const bf16x8*)&Bs[rowb * 64 + (((kc * 4 + quad) ^ (rowb & 7)) << 3)];
      }
#pragma unroll
      for (int mi = 0; mi < 4; ++mi)
#pragma unroll
        for (int ni = 0; ni < 4; ++ni)
          acc[mi][ni] = __builtin_amdgcn_mfma_f32_16x16x32_bf16(af[mi], bfr[ni],
                                                                acc[mi][ni], 0, 0, 0);
    }
  }

  // ---------------- epilogue
  __syncthreads();                       // all As/Bs reads done before overwrite
  const int s = blockIdx.x;              // 0..47: head-slice
  const int b = m0 >> 11;
  const int tloc = m0 & 2047;
  bf16 (*tile)[136] = (bf16(*)[136])smem;

  if (s < 32) {
    // acc -> tile[t-row][col]
#pragma unroll
    for (int mi = 0; mi < 4; ++mi) {
      int row = wm * 64 + mi * 16 + quad * 4;
#pragma unroll
      for (int ni = 0; ni < 4; ++ni) {
        int col = wn * 64 + ni * 16 + li;
#pragma unroll
        for (int r = 0; r < 4; ++r)
          tile[row + r][col] = (bf16)acc[mi][ni][r];
      }
    }
    __syncthreads();

    // per-row RMSNorm + RoPE: 16-lane group owns a row; lane li holds
    // cols [4li..4li+3] and [64+4li..64+4li+3] (RoPE pairs d,d+64).
    const float* w = (s < 16) ? qw : kw;
    bf16* Og = (s < 16) ? Qg : Kg;
    const int h = s & 15;
    const size_t hb = (size_t)(b * Hh + h) * Tt;
    float w1[4], w2[4];
#pragma unroll
    for (int j = 0; j < 4; ++j) { w1[j] = w[li * 4 + j]; w2[j] = w[64 + li * 4 + j]; }
#pragma unroll
    for (int it = 0; it < 8; ++it) {
      int row = wave * 32 + it * 4 + quad;
      int t = tloc + row;
      bf16x4 x1 = *(const bf16x4*)&tile[row][li * 4];
      bf16x4 x2 = *(const bf16x4*)&tile[row][64 + li * 4];
      float f1[4], f2[4];
      float ss = 0.f;
#pragma unroll
      for (int j = 0; j < 4; ++j) {
        f1[j] = (float)x1[j]; f2[j] = (float)x2[j];
        ss += f1[j] * f1[j] + f2[j] * f2[j];
      }
#pragma unroll
      for (int o = 1; o < 16; o <<= 1) ss += __shfl_xor(ss, o);
      float rn = rsqrtf(ss * (1.0f / 128.0f) + EPSf);
      const float4* rp = (const float4*)(rope + t * 64 + li * 4);
      float4 ra = rp[0], rb = rp[1];   // {cs0,sn0,cs1,sn1},{cs2,sn2,cs3,sn3}
      float cs[4] = {ra.x, ra.z, rb.x, rb.z};
      float sn[4] = {ra.y, ra.w, rb.y, rb.w};
      bf16x4 o1, o2;
#pragma unroll
      for (int j = 0; j < 4; ++j) {
        float a1 = f1[j] * rn * w1[j], a2 = f2[j] * rn * w2[j];
        o1[j] = (bf16)(a1 * cs[j] - a2 * sn[j]);
        o2[j] = (bf16)(a2 * cs[j] + a1 * sn[j]);
      }
      size_t ob = (hb + t) * Dd + li * 4;
      *(bf16x4*)(Og + ob)      = o1;
      *(bf16x4*)(Og + ob + 64) = o2;
    }
  } else {
    // V: store acc pre-transposed -> tile[d][t-row], then vector rows out.
#pragma unroll
    for (int mi = 0; mi < 4; ++mi) {
      int row = wm * 64 + mi * 16 + quad * 4;
#pragma unroll
      for (int ni = 0; ni < 4; ++ni) {
        int col = wn * 64 + ni * 16 + li;
#pragma unroll
        for (int r = 0; r < 4; ++r)
          tile[col][row + r] = (bf16)acc[mi][ni][r];
      }
    }
    __syncthreads();
    const int h = s - 32;
    const size_t hb = (size_t)(b * Hh + h) * Dd;
#pragma unroll
    for (int it = 0; it < 8; ++it) {
      int d  = it * 16 + (tid >> 4);
      int t0 = (tid & 15) * 8;
      bf16x8 v = *(const bf16x8*)&tile[d][t0];
      *(bf16x8*)(VgT + (hb + d) * Tt + tloc + t0) = v;
    }
  }
}

// ------------------------------------------------------------------ GEMM 256x128, 8-wave
// (round-4 schedule, kept for the proj GEMM: 16x16 = 256 wg = 1 clean round)
template <typename OutT>
__global__ __launch_bounds__(512, 2) void gemm256(const bf16* __restrict__ A,
                                                  const bf16* __restrict__ Bt,
                                                  OutT* __restrict__ Cm,
                                                  int Nn, int Kk) {
  __shared__ __align__(16) bf16 As[2][256 * 64];
  __shared__ __align__(16) bf16 Bs[2][128 * 64];
  const int tid = threadIdx.x;
  const int wave = tid >> 6, lane = tid & 63;
  const int quad = lane >> 4, li = lane & 15;
  const int wm = wave >> 2, wn = wave & 3;  // 2(M) x 4(N)

  const int nwg = gridDim.x * gridDim.y;
  const int wg  = blockIdx.y * gridDim.x + blockIdx.x;
  const int swz = (wg & 7) * (nwg >> 3) + (wg >> 3);
  const int m0 = (swz / gridDim.x) * 256;
  const int n0 = (swz % gridDim.x) * 128;

  const int NT = Kk >> 6;
  const int lrow = lane >> 3;
  const int lchk = (lane & 7) ^ lrow;

  auto stageA = [&](int tt, int h, int cb) {
    int kt = (tt < NT ? tt : NT - 1) << 6;
#pragma unroll
    for (int j = 0; j < 2; ++j) {
      int seg = j * 8 + wave;
      int r0 = ((seg >> 3) << 7) + (h << 6) + ((seg & 7) << 3);
      gl_lds16(A + (size_t)(m0 + r0 + lrow) * Kk + kt + (lchk << 3),
               &As[cb][r0 * 64]);
    }
  };
  auto stageB = [&](int tt, int cb) {
    int kt = (tt < NT ? tt : NT - 1) << 6;
#pragma unroll
    for (int j = 0; j < 2; ++j) {
      int seg = j * 8 + wave;
      int r0 = seg << 3;
      gl_lds16(Bt + (size_t)(n0 + r0 + lrow) * Kk + kt + (lchk << 3),
               &Bs[cb][r0 * 64]);
    }
  };

  f32x4 acc[8][2] = {};
  bf16x8 afr[4][2], bfr[2][2];

  auto rdA = [&](int h, int cb) {
#pragma unroll
    for (int mi = 0; mi < 4; ++mi) {
      int r = wm * 128 + h * 64 + mi * 16 + li;
#pragma unroll
      for (int kc = 0; kc < 2; ++kc)
        afr[mi][kc] = *(const bf16x8*)&As[cb][r * 64 + (((kc * 4 + quad) ^ (r & 7)) << 3)];
    }
  };
  auto rdB = [&](int cb) {
#pragma unroll
    for (int nj = 0; nj < 2; ++nj) {
      int r = wn * 32 + nj * 16 + li;
#pragma unroll
      for (int kc = 0; kc < 2; ++kc)
        bfr[nj][kc] = *(const bf16x8*)&Bs[cb][r * 64 + (((kc * 4 + quad) ^ (r & 7)) << 3)];
    }
  };
  auto mmac = [&](int mo) {
    __builtin_amdgcn_s_setprio(1);
#pragma unroll
    for (int kc = 0; kc < 2; ++kc)
#pragma unroll
      for (int mi = 0; mi < 4; ++mi)
#pragma unroll
        for (int nj = 0; nj < 2; ++nj)
          acc[mo + mi][nj] = __builtin_amdgcn_mfma_f32_16x16x32_bf16(
              afr[mi][kc], bfr[nj][kc], acc[mo + mi][nj], 0, 0, 0);
    __builtin_amdgcn_s_setprio(0);
  };

  auto tile = [&](int t, int cur, int nxt) {
    rdA(0, cur); rdB(cur);
    stageA(t + 1, 1, nxt);
    asm volatile("s_waitcnt lgkmcnt(8)" ::: "memory");
    __builtin_amdgcn_s_barrier();
    asm volatile("s_waitcnt lgkmcnt(0)" ::: "memory");
    __builtin_amdgcn_sched_barrier(0);
    mmac(0);
    asm volatile("s_waitcnt vmcnt(6)" ::: "memory");
    __builtin_amdgcn_s_barrier();
    rdA(1, cur);
    stageA(t + 2, 0, cur);
    stageB(t + 2, cur);
    __builtin_amdgcn_s_barrier();
    asm volatile("s_waitcnt lgkmcnt(0)" ::: "memory");
    __builtin_amdgcn_sched_barrier(0);
    mmac(4);
    asm volatile("s_waitcnt vmcnt(6)" ::: "memory");
    __builtin_amdgcn_s_barrier();
  };

  stageA(0, 0, 0); stageB(0, 0); stageA(0, 1, 0);
  stageA(1, 0, 1); stageB(1, 1);
  asm volatile("s_waitcnt vmcnt(6)" ::: "memory");
  __builtin_amdgcn_s_barrier();

  for (int t = 0; t < NT; t += 2) {
    tile(t, 0, 1);
    tile(t + 1, 1, 0);
  }
  asm volatile("s_waitcnt vmcnt(0)" ::: "memory");

#pragma unroll
  for (int mi = 0; mi < 8; ++mi) {
    int row = m0 + wm * 128 + mi * 16 + quad * 4;
#pragma unroll
    for (int nj = 0; nj < 2; ++nj) {
      int col = n0 + wn * 32 + nj * 16 + li;
#pragma unroll
      for (int r = 0; r < 4; ++r)
        Cm[(size_t)(row + r) * Nn + col] = (OutT)acc[mi][nj][r];
    }
  }
}

// ------------------------------------------------------------------ attention
// Single q-tile per block, grid 32bh x 32qt (qt descending), 1024 blocks.
// Exact-bound softmax: q,k RMS-normed (w=1) + RoPE norm-preserving + scale
// 1/128 => |s| <= ~1.01 (Cauchy-Schwarz). No max tracking, no o-rescale;
// L accumulated per-lane, reduced ONCE at the end.
// T14 async-staged pipeline (see round-3 notes).
__global__ __launch_bounds__(256, 3) void attn(const bf16* __restrict__ Qg,
                                               const bf16* __restrict__ Kg,
                                               const bf16* __restrict__ VgT,
                                               bf16* __restrict__ Yg) {
  __shared__ __align__(16) bf16 Kl[64 * 128];
  __shared__ __align__(16) bf16 Vl[128 * 64];
  __shared__ __align__(16) bf16 Pl[4 * 16 * 72];
  const int bh = blockIdx.x;
  const int qt = (int)gridDim.y - 1 - (int)blockIdx.y;  // long blocks first
  const int b = bh >> 4, h = bh & 15;
  const int tid = threadIdx.x, wave = tid >> 6, lane = tid & 63;
  const int quad = lane >> 4, li = lane & 15;
  const int q0 = qt * 64;

  const bf16* Qbase = Qg + ((size_t)bh * Tt + q0 + wave * 16 + li) * Dd;
  bf16x8 qf[4];
#pragma unroll
  for (int kc = 0; kc < 4; ++kc) qf[kc] = *(const bf16x8*)(Qbase + kc * 32 + quad * 8);

  f32x4 o[8] = {};
  float L[4] = {};
  bf16* Pw = &Pl[wave * 16 * 72];

  bf16x8 kreg[4];
  auto loadK = [&](int k0) {
#pragma unroll
    for (int j = 0; j < 4; ++j) {
      int c = j * 256 + tid;
      int r = c >> 4, cc = c & 15;
      kreg[j] = *(const bf16x8*)(Kg + ((size_t)bh * Tt + k0 + r) * Dd + ((cc ^ (r & 7)) << 3));
    }
  };
  auto stageV = [&](int k0) {
#pragma unroll
    for (int j = 0; j < 4; ++j) {
      int c = j * 256 + tid;
      int r = c >> 3, cc = c & 7;
      gl_lds16(VgT + ((size_t)bh * Dd + r) * Tt + k0 + ((cc ^ (r & 7)) << 3), &Vl[c * 8]);
    }
  };

  loadK(0);
  stageV(0);

  for (int kt = 0; kt <= qt; ++kt) {
    asm volatile("s_waitcnt vmcnt(4)" ::: "memory");
#pragma unroll
    for (int j = 0; j < 4; ++j) {
      int c = j * 256 + tid;
      *(bf16x8*)&Kl[c * 8] = kreg[j];
    }
    if (kt < qt) loadK(kt * 64 + 64);
    asm volatile("s_waitcnt lgkmcnt(0)" ::: "memory");
    __builtin_amdgcn_s_barrier();
    __builtin_amdgcn_sched_barrier(0);

    f32x4 s4[4] = {};
#pragma unroll
    for (int nt = 0; nt < 4; ++nt) {
      int key = nt * 16 + li;
#pragma unroll
      for (int kc = 0; kc < 4; ++kc) {
        bf16x8 kf = *(const bf16x8*)&Kl[key * 128 + (((kc * 4 + quad) ^ (key & 7)) << 3)];
        s4[nt] = __builtin_amdgcn_mfma_f32_16x16x32_bf16(qf[kc], kf, s4[nt], 0, 0, 0);
      }
    }
    const bool diag = (kt == qt);
#pragma unroll
    for (int nt = 0; nt < 4; ++nt)
#pragma unroll
      for (int r = 0; r < 4; ++r) {
        float e = __expf(s4[nt][r] * SCALE);
        if (diag && (nt * 16 + li > wave * 16 + quad * 4 + r)) e = 0.f;
        L[r] += e;
        Pw[(quad * 4 + r) * 72 + nt * 16 + li] = (bf16)e;
      }
    if (kt < qt) { asm volatile("s_waitcnt vmcnt(4)" ::: "memory"); }
    else         { asm volatile("s_waitcnt vmcnt(0)" ::: "memory"); }
    __builtin_amdgcn_s_barrier();
    __builtin_amdgcn_sched_barrier(0);

#pragma unroll
    for (int kc = 0; kc < 2; ++kc) {
      bf16x8 pf = *(const bf16x8*)&Pw[li * 72 + kc * 32 + quad * 8];
#pragma unroll
      for (int u = 0; u < 8; ++u) {
        bf16x8 vf = *(const bf16x8*)&Vl[(u * 16 + li) * 64 + (((kc * 4 + quad) ^ (li & 7)) << 3)];
        o[u] = __builtin_amdgcn_mfma_f32_16x16x32_bf16(pf, vf, o[u], 0, 0, 0);
      }
    }
    asm volatile("" ::: "memory");
    __builtin_amdgcn_s_barrier();
    __builtin_amdgcn_sched_barrier(0);
    if (kt < qt) stageV(kt * 64 + 64);
  }

  float inv[4];
#pragma unroll
  for (int r = 0; r < 4; ++r) {
    float s0 = L[r];
#pragma unroll
    for (int off = 1; off < 16; off <<= 1) s0 += __shfl_xor(s0, off);
    inv[r] = 1.0f / s0;
  }
  int trow = q0 + wave * 16 + quad * 4;
#pragma unroll
  for (int u = 0; u < 8; ++u) {
    int col = h * Dd + u * 16 + li;
#pragma unroll
    for (int r = 0; r < 4; ++r)
      Yg[(size_t)(b * Tt + trow + r) * Cc_ + col] = (bf16)(o[u][r] * inv[r]);
  }
}

// ------------------------------------------------------------------ launch
extern "C" void kernel_launch(void* const* d_in, const int* in_sizes, int n_in,
                              void* d_out, int out_size, void* d_ws, size_t ws_size,
                              hipStream_t stream) {
  const float* x      = (const float*)d_in[0];
  const float* w_qkv  = (const float*)d_in[1];
  const float* w_proj = (const float*)d_in[2];
  const float* qnw    = (const float*)d_in[3];
  const float* knw    = (const float*)d_in[4];
  float* out = (float*)d_out;

  // workspace partition (bf16 elements)
  bf16* xb     = (bf16*)d_ws;                   // dead after fused qkv GEMM
  bf16* wqkvT  = xb + (size_t)Mm_ * Cc_;
  bf16* wprojT = wqkvT + (size_t)N1 * Cc_;
  bf16* Qg     = wprojT + (size_t)Cc_ * Cc_;
  bf16* Kg     = Qg + (size_t)Bb * Hh * Tt * Dd;
  bf16* VgT    = Kg + (size_t)Bb * Hh * Tt * Dd;
  float2* rope = (float2*)(VgT + (size_t)Bb * Hh * Tt * Dd);  // 1 MB, 8B-aligned
  bf16* Yg     = xb;    // alias: xb dead by the time attn writes Yg

  hipLaunchKernelGGL(rope_tab, dim3(Tt * 64 / 256), dim3(256), 0, stream, rope);
  hipLaunchKernelGGL(cvt_bf16, dim3((Mm_ * Cc_ / 4) / 256), dim3(256), 0, stream,
                     x, xb, Mm_ * Cc_);
  hipLaunchKernelGGL(transpose_cvt, dim3(N1 / 64, Cc_ / 64), dim3(256), 0, stream,
                     w_qkv, wqkvT, Cc_, N1);
  hipLaunchKernelGGL(transpose_cvt, dim3(Cc_ / 64, Cc_ / 64), dim3(256), 0, stream,
                     w_proj, wprojT, Cc_, Cc_);
  // fused: GEMM + RMSNorm + RoPE + rearrange + V-transpose (replaces 3 kernels)
  hipLaunchKernelGGL(gemm_qkv_fused, dim3(N1 / 128, Mm_ / 128), dim3(256), 0, stream,
                     xb, wqkvT, qnw, knw, rope, Qg, Kg, VgT);
  hipLaunchKernelGGL(attn, dim3(Bb * Hh, Tt / 64), dim3(256), 0, stream,
                     Qg, Kg, VgT, Yg);
  // proj GEMM: 256x128 tile, 16x16 = 256 wg = exactly 1 round
  hipLaunchKernelGGL(gemm256<float>, dim3(Cc_ / 128, Mm_ / 256), dim3(512), 0, stream,
                     Yg, wprojT, out, Cc_, Cc_);
}